// Round 15
// baseline (528.154 us; speedup 1.0000x reference)
//
#include <hip/hip_runtime.h>
#include <hip/hip_bf16.h>

#define DIM 256
#define GRP 4                     // rows per group (one wave per group in agg)
#define CAP8 56                   // capacity per (xcd, group) sublist (mean 16, 10 sigma)
#define OVF_CAP 65536

typedef short s16x8 __attribute__((ext_vector_type(8)));
typedef float f32x4 __attribute__((ext_vector_type(4)));

__device__ inline unsigned short f32_bf16_rne(float f) {
    unsigned u = __float_as_uint(f);
    u += 0x7FFFu + ((u >> 16) & 1u);
    return (unsigned short)(u >> 16);
}
__device__ inline float bf16_f32(unsigned short h) {
    return __uint_as_float(((unsigned)h) << 16);
}
__device__ inline float4 bf16x4_f32(uint2 p) {
    float4 r;
    r.x = __uint_as_float(p.x << 16);
    r.y = __uint_as_float(p.x & 0xFFFF0000u);
    r.z = __uint_as_float(p.y << 16);
    r.w = __uint_as_float(p.y & 0xFFFF0000u);
    return r;
}

// ---------------- W [256][256] f32 -> bf16 ----------------
__global__ __launch_bounds__(256) void prep_w(const float* __restrict__ W,
                                              unsigned short* __restrict__ Wh) {
    int i = blockIdx.x * 256 + threadIdx.x;
    Wh[i] = f32_bf16_rne(W[i]);
}

// ---------------- device bodies ----------------
__device__ __forceinline__ void gemm_body(const float* __restrict__ X,
                                          const unsigned short* __restrict__ Wh,
                                          unsigned short* __restrict__ H, int N, int gb,
                                          unsigned short* xh, unsigned short* xl) {
    const int tid = threadIdx.x;
    const int lane = tid & 63;
    const int wv = tid >> 6;
    const int bm = gb * 64;

    const int srow = tid & 63;
    const int schunk = tid >> 6;
    const int grow = bm + srow;
    const bool rowok = grow < N;
    const float* xsrc = X + (size_t)grow * DIM + schunk * 8;
    const int swch = srow * 4 + (schunk ^ ((srow >> 1) & 3));

    const int frow = lane & 15;
    const int fch = lane >> 4;

    f32x4 acc[4][4] = {};

    for (int k0 = 0; k0 < DIM; k0 += 32) {
        float v[8];
        if (rowok) {
            f32x4 a = __builtin_nontemporal_load((const f32x4*)(xsrc + k0));
            f32x4 b = __builtin_nontemporal_load((const f32x4*)(xsrc + k0 + 4));
            v[0] = a[0]; v[1] = a[1]; v[2] = a[2]; v[3] = a[3];
            v[4] = b[0]; v[5] = b[1]; v[6] = b[2]; v[7] = b[3];
        } else {
#pragma unroll
            for (int e = 0; e < 8; ++e) v[e] = 0.f;
        }
        unsigned hh[8], ll[8];
#pragma unroll
        for (int e = 0; e < 8; ++e) {
            unsigned short hu = f32_bf16_rne(v[e]);
            hh[e] = hu;
            ll[e] = f32_bf16_rne(v[e] - bf16_f32(hu));
        }
        uint4 hv = make_uint4(hh[0] | (hh[1] << 16), hh[2] | (hh[3] << 16),
                              hh[4] | (hh[5] << 16), hh[6] | (hh[7] << 16));
        uint4 lv = make_uint4(ll[0] | (ll[1] << 16), ll[2] | (ll[3] << 16),
                              ll[4] | (ll[5] << 16), ll[6] | (ll[7] << 16));
        ((uint4*)xh)[swch] = hv;
        ((uint4*)xl)[swch] = lv;
        __syncthreads();

        s16x8 ah[4], al[4], bh[4];
#pragma unroll
        for (int i = 0; i < 4; ++i) {
            int row = i * 16 + frow;
            int rch = row * 4 + (fch ^ ((row >> 1) & 3));
            ah[i] = __builtin_bit_cast(s16x8, ((const uint4*)xh)[rch]);
            al[i] = __builtin_bit_cast(s16x8, ((const uint4*)xl)[rch]);
        }
#pragma unroll
        for (int j = 0; j < 4; ++j) {
            size_t off = (size_t)(wv * 64 + j * 16 + frow) * DIM + k0 + fch * 8;
            bh[j] = __builtin_bit_cast(s16x8, *(const uint4*)(Wh + off));
        }
#pragma unroll
        for (int i = 0; i < 4; ++i)
#pragma unroll
            for (int j = 0; j < 4; ++j) {
                acc[i][j] = __builtin_amdgcn_mfma_f32_16x16x32_bf16(ah[i], bh[j], acc[i][j], 0, 0, 0);
                acc[i][j] = __builtin_amdgcn_mfma_f32_16x16x32_bf16(al[i], bh[j], acc[i][j], 0, 0, 0);
            }
        __syncthreads();
    }

#pragma unroll
    for (int i = 0; i < 4; ++i)
#pragma unroll
        for (int r = 0; r < 4; ++r) {
            int row = bm + i * 16 + fch * 4 + r;
            if (row < N) {
#pragma unroll
                for (int j = 0; j < 4; ++j)
                    H[(size_t)row * DIM + wv * 64 + j * 16 + frow] = f32_bf16_rne(acc[i][j][r]);
            }
        }
}

__device__ __forceinline__ void scatter_body(const int* __restrict__ rows,
                                             const int* __restrict__ cols,
                                             const float* __restrict__ vals,
                                             int* __restrict__ cur,
                                             unsigned long long* __restrict__ buckets,
                                             uint4* __restrict__ ovf,
                                             int* __restrict__ ovf_cnt,
                                             int nE, int B4, int sb, int nScat) {
    unsigned xcd;
    asm volatile("s_getreg_b32 %0, hwreg(HW_REG_XCC_ID)" : "=s"(xcd));
    xcd &= 7;

    int i = sb * 256 + threadIdx.x;
    int st = nScat * 256;
    for (int e = i; e < nE; e += st) {
        int r = __builtin_nontemporal_load(rows + e);
        unsigned c = (unsigned)__builtin_nontemporal_load(cols + e);
        unsigned vb = __builtin_bit_cast(unsigned, __builtin_nontemporal_load(vals + e));
        int cell = (int)xcd * B4 + (r >> 2);
        int p = atomicAdd(&cur[cell], 1);
        if (p < CAP8) {
            unsigned lo = c | ((unsigned)(r & 3) << 17);
            buckets[(size_t)cell * CAP8 + p] = (unsigned long long)lo | ((unsigned long long)vb << 32);
        } else {
            int q = atomicAdd(ovf_cnt, 1);
            if (q < OVF_CAP) ovf[q] = make_uint4((unsigned)r, c, vb, 0u);
        }
    }
}

// ---------------- fused: every 7th block (bid%7==3) scatters; rest run gemm tiles ----------------
__global__ __launch_bounds__(256) void fused_sg(const float* __restrict__ X,
                                                const unsigned short* __restrict__ Wh,
                                                unsigned short* __restrict__ H,
                                                const int* __restrict__ rows,
                                                const int* __restrict__ cols,
                                                const float* __restrict__ vals,
                                                int* __restrict__ cur,
                                                unsigned long long* __restrict__ buckets,
                                                uint4* __restrict__ ovf,
                                                int* __restrict__ ovf_cnt,
                                                int N, int nE, int B4, int nScat) {
    __shared__ __align__(16) unsigned short xh[64 * 32];
    __shared__ __align__(16) unsigned short xl[64 * 32];

    const int bid = blockIdx.x;
    if (bid % 7 == 3) {
        scatter_body(rows, cols, vals, cur, buckets, ovf, ovf_cnt, nE, B4, bid / 7, nScat);
    } else {
        int gidx = bid - (bid + 3) / 7;   // rank among non-scatter blocks
        gemm_body(X, Wh, H, N, gidx, xh, xl);
    }
}

// ---------------- standalone gemm (fallback path) ----------------
__global__ __launch_bounds__(256) void gemm_mfma(const float* __restrict__ X,
                                                 const unsigned short* __restrict__ Wh,
                                                 unsigned short* __restrict__ H, int N) {
    __shared__ __align__(16) unsigned short xh[64 * 32];
    __shared__ __align__(16) unsigned short xl[64 * 32];
    gemm_body(X, Wh, H, N, blockIdx.x, xh, xl);
}

// ---------------- aggregation: one WAVE per 4-row group (R12 verbatim) ----------------
__global__ __launch_bounds__(256) void bucket_agg4(const unsigned short* __restrict__ hb,
                                                   const unsigned long long* __restrict__ buckets,
                                                   const int* __restrict__ cur,
                                                   float* __restrict__ out, int N, int B4) {
    const int lane = threadIdx.x & 63;
    const int g = (blockIdx.x * 256 + threadIdx.x) >> 6;
    if (g >= B4) return;

    f32x4 a0 = {0,0,0,0}, a1 = {0,0,0,0}, a2 = {0,0,0,0}, a3 = {0,0,0,0};

#define ACCUM(e, gth)                                                        \
    {                                                                        \
        float vv = __uint_as_float((unsigned)((e) >> 32));                   \
        int idx = (int)(((unsigned)(e) >> 17) & 3u);                         \
        float4 f = bf16x4_f32(gth);                                          \
        f32x4 d = {vv * f.x, vv * f.y, vv * f.z, vv * f.w};                  \
        switch (idx) {                                                       \
            case 0: a0 += d; break;  case 1: a1 += d; break;                 \
            case 2: a2 += d; break;  default: a3 += d; break;                \
        }                                                                    \
    }

    for (int x = 0; x < 8; ++x) {
        const int cell = x * B4 + g;
        const int cnt = min(cur[cell], CAP8);
        const unsigned long long* p = buckets + (size_t)cell * CAP8;

        int j = 0;
        for (; j + 8 <= cnt; j += 8) {
            unsigned long long e0 = __builtin_nontemporal_load(p + j);
            unsigned long long e1 = __builtin_nontemporal_load(p + j + 1);
            unsigned long long e2 = __builtin_nontemporal_load(p + j + 2);
            unsigned long long e3 = __builtin_nontemporal_load(p + j + 3);
            unsigned long long e4 = __builtin_nontemporal_load(p + j + 4);
            unsigned long long e5 = __builtin_nontemporal_load(p + j + 5);
            unsigned long long e6 = __builtin_nontemporal_load(p + j + 6);
            unsigned long long e7 = __builtin_nontemporal_load(p + j + 7);
            uint2 g0 = *(const uint2*)(hb + (size_t)((unsigned)e0 & 0x1FFFFu) * DIM + lane * 4);
            uint2 g1 = *(const uint2*)(hb + (size_t)((unsigned)e1 & 0x1FFFFu) * DIM + lane * 4);
            uint2 g2 = *(const uint2*)(hb + (size_t)((unsigned)e2 & 0x1FFFFu) * DIM + lane * 4);
            uint2 g3 = *(const uint2*)(hb + (size_t)((unsigned)e3 & 0x1FFFFu) * DIM + lane * 4);
            uint2 g4 = *(const uint2*)(hb + (size_t)((unsigned)e4 & 0x1FFFFu) * DIM + lane * 4);
            uint2 g5 = *(const uint2*)(hb + (size_t)((unsigned)e5 & 0x1FFFFu) * DIM + lane * 4);
            uint2 g6 = *(const uint2*)(hb + (size_t)((unsigned)e6 & 0x1FFFFu) * DIM + lane * 4);
            uint2 g7 = *(const uint2*)(hb + (size_t)((unsigned)e7 & 0x1FFFFu) * DIM + lane * 4);
            ACCUM(e0, g0) ACCUM(e1, g1) ACCUM(e2, g2) ACCUM(e3, g3)
            ACCUM(e4, g4) ACCUM(e5, g5) ACCUM(e6, g6) ACCUM(e7, g7)
        }
        for (; j < cnt; ++j) {
            unsigned long long e = __builtin_nontemporal_load(p + j);
            uint2 gv = *(const uint2*)(hb + (size_t)((unsigned)e & 0x1FFFFu) * DIM + lane * 4);
            ACCUM(e, gv)
        }
    }
#undef ACCUM

    const int r0 = g * GRP;
#define STORE_ROW(i, acc) \
    { int r = r0 + (i); if (r < N) __builtin_nontemporal_store(acc, (f32x4*)(out + (size_t)r * DIM + lane * 4)); }
    STORE_ROW(0, a0) STORE_ROW(1, a1) STORE_ROW(2, a2) STORE_ROW(3, a3)
#undef STORE_ROW
}

// ---------------- overflow fixup (expected count: 0) ----------------
__global__ __launch_bounds__(256) void ovf_fix(const unsigned short* __restrict__ hb,
                                               const uint4* __restrict__ ovf,
                                               const int* __restrict__ ovf_cnt,
                                               float* __restrict__ out) {
    const int n = min(*ovf_cnt, OVF_CAP);
    const int lane = threadIdx.x & 63;
    const int w = (blockIdx.x * 256 + threadIdx.x) >> 6;
    const int nw = gridDim.x * 4;
    for (int e = w; e < n; e += nw) {
        uint4 t = ovf[e];
        float vv = __uint_as_float(t.z);
        float4 f = bf16x4_f32(*(const uint2*)(hb + (size_t)t.y * DIM + lane * 4));
        float* op = out + (size_t)t.x * DIM + lane * 4;
        atomicAdd(op + 0, vv * f.x);
        atomicAdd(op + 1, vv * f.y);
        atomicAdd(op + 2, vv * f.z);
        atomicAdd(op + 3, vv * f.w);
    }
}

// ---------------- fallback (atomics) ----------------
__global__ __launch_bounds__(256) void edge_scatter(const unsigned short* __restrict__ hb,
                                                    const int* __restrict__ rows,
                                                    const int* __restrict__ cols,
                                                    const float* __restrict__ vals,
                                                    float* __restrict__ out, int nE) {
    const int lane = threadIdx.x & 63;
    const int wave = (blockIdx.x * blockDim.x + threadIdx.x) >> 6;
    const int nWaves = (gridDim.x * blockDim.x) >> 6;
    for (int e = wave; e < nE; e += nWaves) {
        const int r = rows[e];
        const int c = cols[e];
        const float v = vals[e];
        float4 f = bf16x4_f32(*(const uint2*)(hb + (size_t)c * DIM + lane * 4));
        float* op = out + (size_t)r * DIM + lane * 4;
        atomicAdd(op + 0, v * f.x);
        atomicAdd(op + 1, v * f.y);
        atomicAdd(op + 2, v * f.z);
        atomicAdd(op + 3, v * f.w);
    }
}

extern "C" void kernel_launch(void* const* d_in, const int* in_sizes, int n_in,
                              void* d_out, int out_size, void* d_ws, size_t ws_size,
                              hipStream_t stream) {
    const float* x    = (const float*)d_in[0];
    const int*   rows = (const int*)d_in[1];
    const int*   cols = (const int*)d_in[2];
    const float* vals = (const float*)d_in[3];
    const float* W    = (const float*)d_in[4];

    float* out = (float*)d_out;
    const int N  = in_sizes[0] / DIM;         // 100000
    const int nE = in_sizes[1];               // 3200000
    const int B4 = (N + GRP - 1) / GRP;       // 25000 groups
    const int cells = 8 * B4;                 // 200000

    auto align256 = [](size_t v) { return (v + 255) & ~(size_t)255; };
    char* ws = (char*)d_ws;

    size_t off_wh   = 0;
    size_t off_h    = align256(off_wh + (size_t)DIM * DIM * 2);
    size_t off_cur  = align256(off_h + (size_t)N * DIM * 2);       // h bf16: 51.2 MB
    size_t off_ovf  = align256(off_cur + (size_t)(cells + 64) * 4);
    size_t off_bkt  = align256(off_ovf + (size_t)OVF_CAP * 16);
    size_t total    = off_bkt + (size_t)cells * CAP8 * 8;          // 89.6 MB buckets

    unsigned short* Wh = (unsigned short*)(ws + off_wh);
    unsigned short* h  = (unsigned short*)(ws + off_h);

    const bool packOK = (N <= (1 << 17));

    prep_w<<<DIM * DIM / 256, 256, 0, stream>>>(W, Wh);

    if (ws_size >= total && packOK) {
        int*   cur     = (int*)(ws + off_cur);
        int*   ovf_cnt = cur + cells;
        uint4* ovf     = (uint4*)(ws + off_ovf);
        unsigned long long* bkt = (unsigned long long*)(ws + off_bkt);

        hipMemsetAsync(cur, 0, (size_t)(cells + 64) * 4, stream);

        // grid: nGemm non-scatter blocks + interleaved scatter blocks (bid%7==3)
        const int nGemm = (N + 63) / 64;                 // 1563
        int nScat = 0;
        for (int it = 0; it < 8; ++it) nScat = (nGemm + nScat + 3) / 7;
        const int grid = nGemm + nScat;                  // 1823, nscat(1823)=260

        fused_sg<<<grid, 256, 0, stream>>>(x, Wh, h, rows, cols, vals,
                                           cur, bkt, ovf, ovf_cnt, N, nE, B4, nScat);

        bucket_agg4<<<(B4 + 3) / 4, 256, 0, stream>>>(h, bkt, cur, out, N, B4);
        ovf_fix<<<32, 256, 0, stream>>>(h, ovf, ovf_cnt, out);
    } else {
        gemm_mfma<<<(N + 63) / 64, 256, 0, stream>>>(x, Wh, h, N);
        hipMemsetAsync(out, 0, (size_t)out_size * sizeof(float), stream);
        edge_scatter<<<2048, 256, 0, stream>>>(h, rows, cols, vals, out, nE);
    }
}

// Round 16
// 451.003 us; speedup vs baseline: 1.1711x; 1.1711x over previous
//
#include <hip/hip_runtime.h>
#include <hip/hip_bf16.h>

#define DIM 256
#define GRP 8                     // rows per group (bucket granularity)
#define CAP8 88                   // capacity per (xcd, group) sublist (mean 32)
#define OVF_CAP 65536

typedef short s16x8 __attribute__((ext_vector_type(8)));
typedef float f32x4 __attribute__((ext_vector_type(4)));

__device__ inline unsigned short f32_bf16_rne(float f) {
    unsigned u = __float_as_uint(f);
    u += 0x7FFFu + ((u >> 16) & 1u);
    return (unsigned short)(u >> 16);
}
__device__ inline float bf16_f32(unsigned short h) {
    return __uint_as_float(((unsigned)h) << 16);
}
__device__ inline float4 bf16x4_f32(uint2 p) {
    float4 r;
    r.x = __uint_as_float(p.x << 16);
    r.y = __uint_as_float(p.x & 0xFFFF0000u);
    r.z = __uint_as_float(p.y << 16);
    r.w = __uint_as_float(p.y & 0xFFFF0000u);
    return r;
}

// ---------------- W [256][256] f32 -> bf16 ----------------
__global__ __launch_bounds__(256) void prep_w(const float* __restrict__ W,
                                              unsigned short* __restrict__ Wh) {
    int i = blockIdx.x * 256 + threadIdx.x;
    Wh[i] = f32_bf16_rne(W[i]);
}

// ---------------- GEMM: H(bf16) = X @ Wh^T via split-x bf16 MFMA ----------------
__global__ __launch_bounds__(256) void gemm_mfma(const float* __restrict__ X,
                                                 const unsigned short* __restrict__ Wh,
                                                 unsigned short* __restrict__ H, int N) {
    __shared__ __align__(16) unsigned short xh[64 * 32];
    __shared__ __align__(16) unsigned short xl[64 * 32];

    const int tid = threadIdx.x;
    const int lane = tid & 63;
    const int wv = tid >> 6;
    const int bm = blockIdx.x * 64;

    const int srow = tid & 63;
    const int schunk = tid >> 6;
    const int grow = bm + srow;
    const bool rowok = grow < N;
    const float* xsrc = X + (size_t)grow * DIM + schunk * 8;
    const int swch = srow * 4 + (schunk ^ ((srow >> 1) & 3));

    const int frow = lane & 15;
    const int fch = lane >> 4;

    f32x4 acc[4][4] = {};

    for (int k0 = 0; k0 < DIM; k0 += 32) {
        float v[8];
        if (rowok) {
            float4 a = *(const float4*)(xsrc + k0);
            float4 b = *(const float4*)(xsrc + k0 + 4);
            v[0] = a.x; v[1] = a.y; v[2] = a.z; v[3] = a.w;
            v[4] = b.x; v[5] = b.y; v[6] = b.z; v[7] = b.w;
        } else {
#pragma unroll
            for (int e = 0; e < 8; ++e) v[e] = 0.f;
        }
        unsigned hh[8], ll[8];
#pragma unroll
        for (int e = 0; e < 8; ++e) {
            unsigned short hu = f32_bf16_rne(v[e]);
            hh[e] = hu;
            ll[e] = f32_bf16_rne(v[e] - bf16_f32(hu));
        }
        uint4 hv = make_uint4(hh[0] | (hh[1] << 16), hh[2] | (hh[3] << 16),
                              hh[4] | (hh[5] << 16), hh[6] | (hh[7] << 16));
        uint4 lv = make_uint4(ll[0] | (ll[1] << 16), ll[2] | (ll[3] << 16),
                              ll[4] | (ll[5] << 16), ll[6] | (ll[7] << 16));
        ((uint4*)xh)[swch] = hv;
        ((uint4*)xl)[swch] = lv;
        __syncthreads();

        s16x8 ah[4], al[4], bh[4];
#pragma unroll
        for (int i = 0; i < 4; ++i) {
            int row = i * 16 + frow;
            int rch = row * 4 + (fch ^ ((row >> 1) & 3));
            ah[i] = __builtin_bit_cast(s16x8, ((const uint4*)xh)[rch]);
            al[i] = __builtin_bit_cast(s16x8, ((const uint4*)xl)[rch]);
        }
#pragma unroll
        for (int j = 0; j < 4; ++j) {
            size_t off = (size_t)(wv * 64 + j * 16 + frow) * DIM + k0 + fch * 8;
            bh[j] = __builtin_bit_cast(s16x8, *(const uint4*)(Wh + off));
        }
#pragma unroll
        for (int i = 0; i < 4; ++i)
#pragma unroll
            for (int j = 0; j < 4; ++j) {
                acc[i][j] = __builtin_amdgcn_mfma_f32_16x16x32_bf16(ah[i], bh[j], acc[i][j], 0, 0, 0);
                acc[i][j] = __builtin_amdgcn_mfma_f32_16x16x32_bf16(al[i], bh[j], acc[i][j], 0, 0, 0);
            }
        __syncthreads();
    }

#pragma unroll
    for (int i = 0; i < 4; ++i)
#pragma unroll
        for (int r = 0; r < 4; ++r) {
            int row = bm + i * 16 + fch * 4 + r;
            if (row < N) {
#pragma unroll
                for (int j = 0; j < 4; ++j)
                    H[(size_t)row * DIM + wv * 64 + j * 16 + frow] = f32_bf16_rne(acc[i][j][r]);
            }
        }
}

// ---------------- edge -> XCD-private 8-row-group bucket append (R11 verbatim) ----------------
__global__ __launch_bounds__(256) void scatter_bucket8(const int* __restrict__ rows,
                                                       const int* __restrict__ cols,
                                                       const float* __restrict__ vals,
                                                       int* __restrict__ cur,
                                                       unsigned long long* __restrict__ buckets,
                                                       uint4* __restrict__ ovf,
                                                       int* __restrict__ ovf_cnt,
                                                       int nE, int B8) {
    unsigned xcd;
    asm volatile("s_getreg_b32 %0, hwreg(HW_REG_XCC_ID)" : "=s"(xcd));
    xcd &= 7;

    int i = blockIdx.x * 256 + threadIdx.x;
    int st = gridDim.x * 256;
    for (int e = i; e < nE; e += st) {
        int r = rows[e];
        unsigned c = (unsigned)cols[e];
        unsigned vb = __float_as_uint(vals[e]);
        int cell = (int)xcd * B8 + (r >> 3);
        int p = atomicAdd(&cur[cell], 1);
        if (p < CAP8) {
            unsigned lo = c | ((unsigned)(r & 7) << 17);
            buckets[(size_t)cell * CAP8 + p] = (unsigned long long)lo | ((unsigned long long)vb << 32);
        } else {
            int q = atomicAdd(ovf_cnt, 1);
            if (q < OVF_CAP) ovf[q] = make_uint4((unsigned)r, c, vb, 0u);
        }
    }
}

// ---------------- aggregation: wave-PAIR per 8-row group, split by sublist ----------------
// Block = 128 threads = 2 waves, one group per block. Wave h scans sublists 4h..4h+3
// (no duplicated work). Wave1 dumps accs to 8KB LDS; wave0 adds + stores.
__global__ __launch_bounds__(128) void bucket_agg8p(const unsigned short* __restrict__ hb,
                                                    const unsigned long long* __restrict__ buckets,
                                                    const int* __restrict__ cur,
                                                    float* __restrict__ out, int N, int B8) {
    __shared__ float red[GRP * DIM];          // 8 KB
    const int lane = threadIdx.x & 63;
    const int half = threadIdx.x >> 6;        // 0 or 1
    const int g = blockIdx.x;                 // grid = B8, no bounds check needed

    f32x4 a0 = {0,0,0,0}, a1 = {0,0,0,0}, a2 = {0,0,0,0}, a3 = {0,0,0,0};
    f32x4 a4 = {0,0,0,0}, a5 = {0,0,0,0}, a6 = {0,0,0,0}, a7 = {0,0,0,0};

#define ACCUM(e, gth)                                                        \
    {                                                                        \
        float vv = __uint_as_float((unsigned)((e) >> 32));                   \
        int idx = (int)(((unsigned)(e) >> 17) & 7u);                         \
        float4 f = bf16x4_f32(gth);                                          \
        f32x4 d = {vv * f.x, vv * f.y, vv * f.z, vv * f.w};                  \
        switch (idx) {                                                       \
            case 0: a0 += d; break;  case 1: a1 += d; break;                 \
            case 2: a2 += d; break;  case 3: a3 += d; break;                 \
            case 4: a4 += d; break;  case 5: a5 += d; break;                 \
            case 6: a6 += d; break;  default: a7 += d; break;                \
        }                                                                    \
    }

    for (int xx = 0; xx < 4; ++xx) {
        const int cell = (half * 4 + xx) * B8 + g;
        const int cnt = min(cur[cell], CAP8);
        const unsigned long long* p = buckets + (size_t)cell * CAP8;

        int j = 0;
        for (; j + 8 <= cnt; j += 8) {
            unsigned long long e0 = __builtin_nontemporal_load(p + j);
            unsigned long long e1 = __builtin_nontemporal_load(p + j + 1);
            unsigned long long e2 = __builtin_nontemporal_load(p + j + 2);
            unsigned long long e3 = __builtin_nontemporal_load(p + j + 3);
            unsigned long long e4 = __builtin_nontemporal_load(p + j + 4);
            unsigned long long e5 = __builtin_nontemporal_load(p + j + 5);
            unsigned long long e6 = __builtin_nontemporal_load(p + j + 6);
            unsigned long long e7 = __builtin_nontemporal_load(p + j + 7);
            uint2 g0 = *(const uint2*)(hb + (size_t)((unsigned)e0 & 0x1FFFFu) * DIM + lane * 4);
            uint2 g1 = *(const uint2*)(hb + (size_t)((unsigned)e1 & 0x1FFFFu) * DIM + lane * 4);
            uint2 g2 = *(const uint2*)(hb + (size_t)((unsigned)e2 & 0x1FFFFu) * DIM + lane * 4);
            uint2 g3 = *(const uint2*)(hb + (size_t)((unsigned)e3 & 0x1FFFFu) * DIM + lane * 4);
            uint2 g4 = *(const uint2*)(hb + (size_t)((unsigned)e4 & 0x1FFFFu) * DIM + lane * 4);
            uint2 g5 = *(const uint2*)(hb + (size_t)((unsigned)e5 & 0x1FFFFu) * DIM + lane * 4);
            uint2 g6 = *(const uint2*)(hb + (size_t)((unsigned)e6 & 0x1FFFFu) * DIM + lane * 4);
            uint2 g7 = *(const uint2*)(hb + (size_t)((unsigned)e7 & 0x1FFFFu) * DIM + lane * 4);
            ACCUM(e0, g0) ACCUM(e1, g1) ACCUM(e2, g2) ACCUM(e3, g3)
            ACCUM(e4, g4) ACCUM(e5, g5) ACCUM(e6, g6) ACCUM(e7, g7)
        }
        for (; j < cnt; ++j) {
            unsigned long long e = __builtin_nontemporal_load(p + j);
            uint2 gv = *(const uint2*)(hb + (size_t)((unsigned)e & 0x1FFFFu) * DIM + lane * 4);
            ACCUM(e, gv)
        }
    }
#undef ACCUM

    if (half == 1) {
        float* rb = red + lane * 4;
#define DUMP(i, acc) *(f32x4*)(rb + (i) * DIM) = acc;
        DUMP(0, a0) DUMP(1, a1) DUMP(2, a2) DUMP(3, a3)
        DUMP(4, a4) DUMP(5, a5) DUMP(6, a6) DUMP(7, a7)
#undef DUMP
    }
    __syncthreads();
    if (half == 0) {
        const float* rb = red + lane * 4;
        const int r0 = g * GRP;
#define FIN(i, acc)                                                              \
        {                                                                        \
            int r = r0 + (i);                                                    \
            if (r < N) {                                                         \
                f32x4 s = acc + *(const f32x4*)(rb + (i) * DIM);                 \
                __builtin_nontemporal_store(s, (f32x4*)(out + (size_t)r * DIM + lane * 4)); \
            }                                                                    \
        }
        FIN(0, a0) FIN(1, a1) FIN(2, a2) FIN(3, a3)
        FIN(4, a4) FIN(5, a5) FIN(6, a6) FIN(7, a7)
#undef FIN
    }
}

// ---------------- overflow fixup (expected count: 0) ----------------
__global__ __launch_bounds__(256) void ovf_fix(const unsigned short* __restrict__ hb,
                                               const uint4* __restrict__ ovf,
                                               const int* __restrict__ ovf_cnt,
                                               float* __restrict__ out) {
    const int n = min(*ovf_cnt, OVF_CAP);
    const int lane = threadIdx.x & 63;
    const int w = (blockIdx.x * 256 + threadIdx.x) >> 6;
    const int nw = gridDim.x * 4;
    for (int e = w; e < n; e += nw) {
        uint4 t = ovf[e];
        float vv = __uint_as_float(t.z);
        float4 f = bf16x4_f32(*(const uint2*)(hb + (size_t)t.y * DIM + lane * 4));
        float* op = out + (size_t)t.x * DIM + lane * 4;
        atomicAdd(op + 0, vv * f.x);
        atomicAdd(op + 1, vv * f.y);
        atomicAdd(op + 2, vv * f.z);
        atomicAdd(op + 3, vv * f.w);
    }
}

// ---------------- fallback (atomics) ----------------
__global__ __launch_bounds__(256) void edge_scatter(const unsigned short* __restrict__ hb,
                                                    const int* __restrict__ rows,
                                                    const int* __restrict__ cols,
                                                    const float* __restrict__ vals,
                                                    float* __restrict__ out, int nE) {
    const int lane = threadIdx.x & 63;
    const int wave = (blockIdx.x * blockDim.x + threadIdx.x) >> 6;
    const int nWaves = (gridDim.x * blockDim.x) >> 6;
    for (int e = wave; e < nE; e += nWaves) {
        const int r = rows[e];
        const int c = cols[e];
        const float v = vals[e];
        float4 f = bf16x4_f32(*(const uint2*)(hb + (size_t)c * DIM + lane * 4));
        float* op = out + (size_t)r * DIM + lane * 4;
        atomicAdd(op + 0, v * f.x);
        atomicAdd(op + 1, v * f.y);
        atomicAdd(op + 2, v * f.z);
        atomicAdd(op + 3, v * f.w);
    }
}

extern "C" void kernel_launch(void* const* d_in, const int* in_sizes, int n_in,
                              void* d_out, int out_size, void* d_ws, size_t ws_size,
                              hipStream_t stream) {
    const float* x    = (const float*)d_in[0];
    const int*   rows = (const int*)d_in[1];
    const int*   cols = (const int*)d_in[2];
    const float* vals = (const float*)d_in[3];
    const float* W    = (const float*)d_in[4];

    float* out = (float*)d_out;
    const int N  = in_sizes[0] / DIM;         // 100000
    const int nE = in_sizes[1];               // 3200000
    const int B8 = (N + GRP - 1) / GRP;       // 12500 groups
    const int cells = 8 * B8;                 // 100000

    auto align256 = [](size_t v) { return (v + 255) & ~(size_t)255; };
    char* ws = (char*)d_ws;

    size_t off_wh   = 0;
    size_t off_h    = align256(off_wh + (size_t)DIM * DIM * 2);
    size_t off_cur  = align256(off_h + (size_t)N * DIM * 2);       // h bf16: 51.2 MB
    size_t off_ovf  = align256(off_cur + (size_t)(cells + 64) * 4);
    size_t off_bkt  = align256(off_ovf + (size_t)OVF_CAP * 16);
    size_t total    = off_bkt + (size_t)cells * CAP8 * 8;          // 70.4 MB buckets

    unsigned short* Wh = (unsigned short*)(ws + off_wh);
    unsigned short* h  = (unsigned short*)(ws + off_h);

    const bool packOK = (N <= (1 << 17));

    prep_w<<<DIM * DIM / 256, 256, 0, stream>>>(W, Wh);

    if (ws_size >= total && packOK) {
        int*   cur     = (int*)(ws + off_cur);
        int*   ovf_cnt = cur + cells;
        uint4* ovf     = (uint4*)(ws + off_ovf);
        unsigned long long* bkt = (unsigned long long*)(ws + off_bkt);

        hipMemsetAsync(cur, 0, (size_t)(cells + 64) * 4, stream);
        scatter_bucket8<<<2048, 256, 0, stream>>>(rows, cols, vals, cur, bkt, ovf, ovf_cnt, nE, B8);

        gemm_mfma<<<(N + 63) / 64, 256, 0, stream>>>(x, Wh, h, N);

        bucket_agg8p<<<B8, 128, 0, stream>>>(h, bkt, cur, out, N, B8);
        ovf_fix<<<32, 256, 0, stream>>>(h, ovf, ovf_cnt, out);
    } else {
        gemm_mfma<<<(N + 63) / 64, 256, 0, stream>>>(x, Wh, h, N);
        hipMemsetAsync(out, 0, (size_t)out_size * sizeof(float), stream);
        edge_scatter<<<2048, 256, 0, stream>>>(h, rows, cols, vals, out, nE);
    }
}

// Round 17
// 444.373 us; speedup vs baseline: 1.1885x; 1.0149x over previous
//
#include <hip/hip_runtime.h>
#include <hip/hip_bf16.h>

#define DIM 256
#define GRP 8                     // rows per group (bucket granularity)
#define CAP8 88                   // capacity per (xcd, group) sublist (mean 32)
#define OVF_CAP 65536

typedef short s16x8 __attribute__((ext_vector_type(8)));
typedef float f32x4 __attribute__((ext_vector_type(4)));

__device__ inline unsigned short f32_bf16_rne(float f) {
    unsigned u = __float_as_uint(f);
    u += 0x7FFFu + ((u >> 16) & 1u);
    return (unsigned short)(u >> 16);
}
__device__ inline float bf16_f32(unsigned short h) {
    return __uint_as_float(((unsigned)h) << 16);
}
__device__ inline float4 bf16x4_f32(uint2 p) {
    float4 r;
    r.x = __uint_as_float(p.x << 16);
    r.y = __uint_as_float(p.x & 0xFFFF0000u);
    r.z = __uint_as_float(p.y << 16);
    r.w = __uint_as_float(p.y & 0xFFFF0000u);
    return r;
}

// ---------------- W [256][256] f32 -> bf16 ----------------
__global__ __launch_bounds__(256) void prep_w(const float* __restrict__ W,
                                              unsigned short* __restrict__ Wh) {
    int i = blockIdx.x * 256 + threadIdx.x;
    Wh[i] = f32_bf16_rne(W[i]);
}

// ---------------- GEMM: H(bf16) = bf16(X) @ Wh^T via bf16 MFMA ----------------
// Single-pass bf16 (no x-lo split): h error ~1e-3 RMS, same order as bf16-h storage.
__global__ __launch_bounds__(256) void gemm_mfma(const float* __restrict__ X,
                                                 const unsigned short* __restrict__ Wh,
                                                 unsigned short* __restrict__ H, int N) {
    __shared__ __align__(16) unsigned short xh[64 * 32];   // 4 KB

    const int tid = threadIdx.x;
    const int lane = tid & 63;
    const int wv = tid >> 6;
    const int bm = blockIdx.x * 64;

    const int srow = tid & 63;
    const int schunk = tid >> 6;
    const int grow = bm + srow;
    const bool rowok = grow < N;
    const float* xsrc = X + (size_t)grow * DIM + schunk * 8;
    const int swch = srow * 4 + (schunk ^ ((srow >> 1) & 3));

    const int frow = lane & 15;
    const int fch = lane >> 4;

    f32x4 acc[4][4] = {};

    for (int k0 = 0; k0 < DIM; k0 += 32) {
        float v[8];
        if (rowok) {
            float4 a = *(const float4*)(xsrc + k0);
            float4 b = *(const float4*)(xsrc + k0 + 4);
            v[0] = a.x; v[1] = a.y; v[2] = a.z; v[3] = a.w;
            v[4] = b.x; v[5] = b.y; v[6] = b.z; v[7] = b.w;
        } else {
#pragma unroll
            for (int e = 0; e < 8; ++e) v[e] = 0.f;
        }
        unsigned hh[8];
#pragma unroll
        for (int e = 0; e < 8; ++e) hh[e] = f32_bf16_rne(v[e]);
        uint4 hv = make_uint4(hh[0] | (hh[1] << 16), hh[2] | (hh[3] << 16),
                              hh[4] | (hh[5] << 16), hh[6] | (hh[7] << 16));
        ((uint4*)xh)[swch] = hv;
        __syncthreads();

        s16x8 ah[4], bh[4];
#pragma unroll
        for (int i = 0; i < 4; ++i) {
            int row = i * 16 + frow;
            int rch = row * 4 + (fch ^ ((row >> 1) & 3));
            ah[i] = __builtin_bit_cast(s16x8, ((const uint4*)xh)[rch]);
        }
#pragma unroll
        for (int j = 0; j < 4; ++j) {
            size_t off = (size_t)(wv * 64 + j * 16 + frow) * DIM + k0 + fch * 8;
            bh[j] = __builtin_bit_cast(s16x8, *(const uint4*)(Wh + off));
        }
#pragma unroll
        for (int i = 0; i < 4; ++i)
#pragma unroll
            for (int j = 0; j < 4; ++j)
                acc[i][j] = __builtin_amdgcn_mfma_f32_16x16x32_bf16(ah[i], bh[j], acc[i][j], 0, 0, 0);
        __syncthreads();
    }

#pragma unroll
    for (int i = 0; i < 4; ++i)
#pragma unroll
        for (int r = 0; r < 4; ++r) {
            int row = bm + i * 16 + fch * 4 + r;
            if (row < N) {
#pragma unroll
                for (int j = 0; j < 4; ++j)
                    H[(size_t)row * DIM + wv * 64 + j * 16 + frow] = f32_bf16_rne(acc[i][j][r]);
            }
        }
}

// ---------------- edge -> XCD-private 8-row-group bucket append (R11 verbatim) ----------------
__global__ __launch_bounds__(256) void scatter_bucket8(const int* __restrict__ rows,
                                                       const int* __restrict__ cols,
                                                       const float* __restrict__ vals,
                                                       int* __restrict__ cur,
                                                       unsigned long long* __restrict__ buckets,
                                                       uint4* __restrict__ ovf,
                                                       int* __restrict__ ovf_cnt,
                                                       int nE, int B8) {
    unsigned xcd;
    asm volatile("s_getreg_b32 %0, hwreg(HW_REG_XCC_ID)" : "=s"(xcd));
    xcd &= 7;

    int i = blockIdx.x * 256 + threadIdx.x;
    int st = gridDim.x * 256;
    for (int e = i; e < nE; e += st) {
        int r = rows[e];
        unsigned c = (unsigned)cols[e];
        unsigned vb = __float_as_uint(vals[e]);
        int cell = (int)xcd * B8 + (r >> 3);
        int p = atomicAdd(&cur[cell], 1);
        if (p < CAP8) {
            unsigned lo = c | ((unsigned)(r & 7) << 17);
            buckets[(size_t)cell * CAP8 + p] = (unsigned long long)lo | ((unsigned long long)vb << 32);
        } else {
            int q = atomicAdd(ovf_cnt, 1);
            if (q < OVF_CAP) ovf[q] = make_uint4((unsigned)r, c, vb, 0u);
        }
    }
}

// ---------------- aggregation: wave-PAIR per 8-row group, split by sublist (R16 verbatim) ----------------
__global__ __launch_bounds__(128) void bucket_agg8p(const unsigned short* __restrict__ hb,
                                                    const unsigned long long* __restrict__ buckets,
                                                    const int* __restrict__ cur,
                                                    float* __restrict__ out, int N, int B8) {
    __shared__ float red[GRP * DIM];          // 8 KB
    const int lane = threadIdx.x & 63;
    const int half = threadIdx.x >> 6;        // 0 or 1
    const int g = blockIdx.x;

    f32x4 a0 = {0,0,0,0}, a1 = {0,0,0,0}, a2 = {0,0,0,0}, a3 = {0,0,0,0};
    f32x4 a4 = {0,0,0,0}, a5 = {0,0,0,0}, a6 = {0,0,0,0}, a7 = {0,0,0,0};

#define ACCUM(e, gth)                                                        \
    {                                                                        \
        float vv = __uint_as_float((unsigned)((e) >> 32));                   \
        int idx = (int)(((unsigned)(e) >> 17) & 7u);                         \
        float4 f = bf16x4_f32(gth);                                          \
        f32x4 d = {vv * f.x, vv * f.y, vv * f.z, vv * f.w};                  \
        switch (idx) {                                                       \
            case 0: a0 += d; break;  case 1: a1 += d; break;                 \
            case 2: a2 += d; break;  case 3: a3 += d; break;                 \
            case 4: a4 += d; break;  case 5: a5 += d; break;                 \
            case 6: a6 += d; break;  default: a7 += d; break;                \
        }                                                                    \
    }

    for (int xx = 0; xx < 4; ++xx) {
        const int cell = (half * 4 + xx) * B8 + g;
        const int cnt = min(cur[cell], CAP8);
        const unsigned long long* p = buckets + (size_t)cell * CAP8;

        int j = 0;
        for (; j + 8 <= cnt; j += 8) {
            unsigned long long e0 = __builtin_nontemporal_load(p + j);
            unsigned long long e1 = __builtin_nontemporal_load(p + j + 1);
            unsigned long long e2 = __builtin_nontemporal_load(p + j + 2);
            unsigned long long e3 = __builtin_nontemporal_load(p + j + 3);
            unsigned long long e4 = __builtin_nontemporal_load(p + j + 4);
            unsigned long long e5 = __builtin_nontemporal_load(p + j + 5);
            unsigned long long e6 = __builtin_nontemporal_load(p + j + 6);
            unsigned long long e7 = __builtin_nontemporal_load(p + j + 7);
            uint2 g0 = *(const uint2*)(hb + (size_t)((unsigned)e0 & 0x1FFFFu) * DIM + lane * 4);
            uint2 g1 = *(const uint2*)(hb + (size_t)((unsigned)e1 & 0x1FFFFu) * DIM + lane * 4);
            uint2 g2 = *(const uint2*)(hb + (size_t)((unsigned)e2 & 0x1FFFFu) * DIM + lane * 4);
            uint2 g3 = *(const uint2*)(hb + (size_t)((unsigned)e3 & 0x1FFFFu) * DIM + lane * 4);
            uint2 g4 = *(const uint2*)(hb + (size_t)((unsigned)e4 & 0x1FFFFu) * DIM + lane * 4);
            uint2 g5 = *(const uint2*)(hb + (size_t)((unsigned)e5 & 0x1FFFFu) * DIM + lane * 4);
            uint2 g6 = *(const uint2*)(hb + (size_t)((unsigned)e6 & 0x1FFFFu) * DIM + lane * 4);
            uint2 g7 = *(const uint2*)(hb + (size_t)((unsigned)e7 & 0x1FFFFu) * DIM + lane * 4);
            ACCUM(e0, g0) ACCUM(e1, g1) ACCUM(e2, g2) ACCUM(e3, g3)
            ACCUM(e4, g4) ACCUM(e5, g5) ACCUM(e6, g6) ACCUM(e7, g7)
        }
        for (; j < cnt; ++j) {
            unsigned long long e = __builtin_nontemporal_load(p + j);
            uint2 gv = *(const uint2*)(hb + (size_t)((unsigned)e & 0x1FFFFu) * DIM + lane * 4);
            ACCUM(e, gv)
        }
    }
#undef ACCUM

    if (half == 1) {
        float* rb = red + lane * 4;
#define DUMP(i, acc) *(f32x4*)(rb + (i) * DIM) = acc;
        DUMP(0, a0) DUMP(1, a1) DUMP(2, a2) DUMP(3, a3)
        DUMP(4, a4) DUMP(5, a5) DUMP(6, a6) DUMP(7, a7)
#undef DUMP
    }
    __syncthreads();
    if (half == 0) {
        const float* rb = red + lane * 4;
        const int r0 = g * GRP;
#define FIN(i, acc)                                                              \
        {                                                                        \
            int r = r0 + (i);                                                    \
            if (r < N) {                                                         \
                f32x4 s = acc + *(const f32x4*)(rb + (i) * DIM);                 \
                __builtin_nontemporal_store(s, (f32x4*)(out + (size_t)r * DIM + lane * 4)); \
            }                                                                    \
        }
        FIN(0, a0) FIN(1, a1) FIN(2, a2) FIN(3, a3)
        FIN(4, a4) FIN(5, a5) FIN(6, a6) FIN(7, a7)
#undef FIN
    }
}

// ---------------- overflow fixup (expected count: 0) ----------------
__global__ __launch_bounds__(256) void ovf_fix(const unsigned short* __restrict__ hb,
                                               const uint4* __restrict__ ovf,
                                               const int* __restrict__ ovf_cnt,
                                               float* __restrict__ out) {
    const int n = min(*ovf_cnt, OVF_CAP);
    const int lane = threadIdx.x & 63;
    const int w = (blockIdx.x * 256 + threadIdx.x) >> 6;
    const int nw = gridDim.x * 4;
    for (int e = w; e < n; e += nw) {
        uint4 t = ovf[e];
        float vv = __uint_as_float(t.z);
        float4 f = bf16x4_f32(*(const uint2*)(hb + (size_t)t.y * DIM + lane * 4));
        float* op = out + (size_t)t.x * DIM + lane * 4;
        atomicAdd(op + 0, vv * f.x);
        atomicAdd(op + 1, vv * f.y);
        atomicAdd(op + 2, vv * f.z);
        atomicAdd(op + 3, vv * f.w);
    }
}

// ---------------- fallback (atomics) ----------------
__global__ __launch_bounds__(256) void edge_scatter(const unsigned short* __restrict__ hb,
                                                    const int* __restrict__ rows,
                                                    const int* __restrict__ cols,
                                                    const float* __restrict__ vals,
                                                    float* __restrict__ out, int nE) {
    const int lane = threadIdx.x & 63;
    const int wave = (blockIdx.x * blockDim.x + threadIdx.x) >> 6;
    const int nWaves = (gridDim.x * blockDim.x) >> 6;
    for (int e = wave; e < nE; e += nWaves) {
        const int r = rows[e];
        const int c = cols[e];
        const float v = vals[e];
        float4 f = bf16x4_f32(*(const uint2*)(hb + (size_t)c * DIM + lane * 4));
        float* op = out + (size_t)r * DIM + lane * 4;
        atomicAdd(op + 0, v * f.x);
        atomicAdd(op + 1, v * f.y);
        atomicAdd(op + 2, v * f.z);
        atomicAdd(op + 3, v * f.w);
    }
}

extern "C" void kernel_launch(void* const* d_in, const int* in_sizes, int n_in,
                              void* d_out, int out_size, void* d_ws, size_t ws_size,
                              hipStream_t stream) {
    const float* x    = (const float*)d_in[0];
    const int*   rows = (const int*)d_in[1];
    const int*   cols = (const int*)d_in[2];
    const float* vals = (const float*)d_in[3];
    const float* W    = (const float*)d_in[4];

    float* out = (float*)d_out;
    const int N  = in_sizes[0] / DIM;         // 100000
    const int nE = in_sizes[1];               // 3200000
    const int B8 = (N + GRP - 1) / GRP;       // 12500 groups
    const int cells = 8 * B8;                 // 100000

    auto align256 = [](size_t v) { return (v + 255) & ~(size_t)255; };
    char* ws = (char*)d_ws;

    size_t off_wh   = 0;
    size_t off_h    = align256(off_wh + (size_t)DIM * DIM * 2);
    size_t off_cur  = align256(off_h + (size_t)N * DIM * 2);       // h bf16: 51.2 MB
    size_t off_ovf  = align256(off_cur + (size_t)(cells + 64) * 4);
    size_t off_bkt  = align256(off_ovf + (size_t)OVF_CAP * 16);
    size_t total    = off_bkt + (size_t)cells * CAP8 * 8;          // 70.4 MB buckets

    unsigned short* Wh = (unsigned short*)(ws + off_wh);
    unsigned short* h  = (unsigned short*)(ws + off_h);

    const bool packOK = (N <= (1 << 17));

    prep_w<<<DIM * DIM / 256, 256, 0, stream>>>(W, Wh);

    if (ws_size >= total && packOK) {
        int*   cur     = (int*)(ws + off_cur);
        int*   ovf_cnt = cur + cells;
        uint4* ovf     = (uint4*)(ws + off_ovf);
        unsigned long long* bkt = (unsigned long long*)(ws + off_bkt);

        hipMemsetAsync(cur, 0, (size_t)(cells + 64) * 4, stream);
        scatter_bucket8<<<2048, 256, 0, stream>>>(rows, cols, vals, cur, bkt, ovf, ovf_cnt, nE, B8);

        gemm_mfma<<<(N + 63) / 64, 256, 0, stream>>>(x, Wh, h, N);

        bucket_agg8p<<<B8, 128, 0, stream>>>(h, bkt, cur, out, N, B8);
        ovf_fix<<<32, 256, 0, stream>>>(h, ovf, ovf_cnt, out);
    } else {
        gemm_mfma<<<(N + 63) / 64, 256, 0, stream>>>(x, Wh, h, N);
        hipMemsetAsync(out, 0, (size_t)out_size * sizeof(float), stream);
        edge_scatter<<<2048, 256, 0, stream>>>(h, rows, cols, vals, out, nE);
    }
}